// Round 7
// baseline (254.406 us; speedup 1.0000x reference)
//
#include <hip/hip_runtime.h>

#define NN 51
#define NVR 52    // V rows padded (row 51 zero)
#define DD 128
#define RS 132    // LDS row stride (words)
#define NT 64

// JAX threefry2x32 (20 rounds), exact.
__device__ __forceinline__ void tf2x32(unsigned k0, unsigned k1, unsigned &x0, unsigned &x1) {
  const unsigned ks2 = k0 ^ k1 ^ 0x1BD11BDAu;
  const unsigned ka[5] = {k1, ks2, k0, k1, ks2};
  const unsigned kb[5] = {ks2 + 1u, k0 + 2u, k1 + 3u, ks2 + 4u, k0 + 5u};
  x0 += k0; x1 += k1;
#pragma unroll
  for (int g = 0; g < 5; ++g) {
    const int r0 = (g & 1) ? 17 : 13;
    const int r1 = (g & 1) ? 29 : 15;
    const int r2 = (g & 1) ? 16 : 26;
    const int r3 = (g & 1) ? 24 : 6;
    x0 += x1; x1 = (x1 << r0) | (x1 >> (32 - r0)); x1 ^= x0;
    x0 += x1; x1 = (x1 << r1) | (x1 >> (32 - r1)); x1 ^= x0;
    x0 += x1; x1 = (x1 << r2) | (x1 >> (32 - r2)); x1 ^= x0;
    x0 += x1; x1 = (x1 << r3) | (x1 >> (32 - r3)); x1 ^= x0;
    x0 += ka[g]; x1 += kb[g];
  }
}

__device__ __forceinline__ float gumbel_from(unsigned k0, unsigned k1, unsigned ctr) {
  unsigned x0 = 0u, x1 = ctr;
  tf2x32(k0, k1, x0, x1);
  const unsigned bits = x0 ^ x1;
  const float fl = __uint_as_float((bits >> 9) | 0x3f800000u) - 1.0f;
  const float TINY = 1.17549435e-38f;
  const float uu = fmaxf(TINY, fl + TINY);
  return -logf(-logf(uu));
}

__device__ __forceinline__ float dot4(const float4 a, const float4 b) {
  return a.x * b.x + a.y * b.y + a.z * b.z + a.w * b.w;
}

__global__ __launch_bounds__(512, 1) void decode_kernel(
    const float* __restrict__ enc, const float* __restrict__ pool_in,
    const float* __restrict__ cap_p, const float* __restrict__ demand,
    const float* __restrict__ fc_w, const float* __restrict__ fc1,
    const float* __restrict__ wq, const float* __restrict__ wk,
    const float* __restrict__ wv, const float* __restrict__ wo,
    const float* __restrict__ wkp, const float* __restrict__ T_p,
    const int* __restrict__ ns_p, const int* __restrict__ greedy_p,
    float* __restrict__ out) {
  __shared__ __align__(16) float Ksh[NN * RS];
  __shared__ __align__(16) float Vsh[NVR * RS];    // row 51 zero
  __shared__ __align__(16) float KP2sh[NN * RS];   // T2=E@wkp -> KP2=T2@wo^T
  __shared__ __align__(16) float EQsh[NN * RS];    // T1=E@fc_top -> EQ=T1@wq
  __shared__ __align__(16) float qpoolL[NT * DD];  // staged enc -> pools -> qpool[t]
  __shared__ __align__(16) float uL[8 * NVR];      // raw softmax numerators e
  __shared__ __align__(16) float gL[DD];
  __shared__ __align__(16) float poolL[DD];
  __shared__ __align__(16) float wrowL[DD];
  __shared__ __align__(16) float partF[512];
  __shared__ float demL[NN];
  __shared__ float logitsL[NN], pertL[NN];
  __shared__ float pgumL[2][NN];
  __shared__ unsigned keysL[2 * NT];
  __shared__ unsigned long long sM1;
  __shared__ float dynS, depotS, lpW0s, lpW1s;
  __shared__ int bestS;

  const int b = blockIdx.x, tid = threadIdx.x;
  const int Bn = gridDim.x;
  const int w = tid >> 6, l = tid & 63;
  int ns = *ns_p; if (ns > NT) ns = NT;
  const int greedy = *greedy_p;
  const float Tval = *T_p;
  const float cap0 = *cap_p;
  const float NINF = -__builtin_inff();

  // ---- stage ----
  {
    const float4* src = (const float4*)(enc + (size_t)b * NN * DD);
    float4* dst = (float4*)qpoolL;
    for (int e = tid; e < NN * DD / 4; e += 512) dst[e] = src[e];
  }
  if (tid < 128) poolL[tid] = pool_in[b * DD + tid];
  if (tid < RS)  Vsh[51 * RS + tid] = 0.f;
  if (tid < NN)  demL[tid] = demand[b * NN + tid];
  if (tid < ns) {  // fold_in(key(1234),0), then partitionable split child t
    unsigned a0 = 0u, a1 = 0u;
    tf2x32(0u, 1234u, a0, a1);
    unsigned x0 = 0u, x1 = (unsigned)tid;
    tf2x32(a0, a1, x0, x1);
    keysL[2 * tid] = x0; keysL[2 * tid + 1] = x1;
  }
  if (tid == 0) { bestS = 0; dynS = cap0; depotS = 1.f; sM1 = 1ull; }
  __syncthreads();  // S1

  float dem_l = (l < NN) ? demL[l] : 0.f;

  // gumbel(0) for step 0 (wave 7)
  if (!greedy && tid >= 448) {
    const int gl = tid - 448;
    if (gl < NN)
      pgumL[0][gl] = gumbel_from(keysL[0], keysL[1], (unsigned)(b * NN + gl));
  }
  // wrow partials: wrow[c] = fc_w[128,:] @ wq[:,c], 4-way depth split
  {
    const int c = tid & 127, qd = tid >> 7;
    const float* fr = fc_w + 128 * DD;
    float s = 0.f;
    for (int j = qd * 32; j < qd * 32 + 32; ++j) s += fr[j] * wq[j * DD + c];
    partF[tid] = s;
  }
  __syncthreads();  // S2
  if (tid < 128)
    wrowL[tid] = partF[tid] + partF[tid + 128] + partF[tid + 256] + partF[tid + 384];

  const int g4 = tid >> 7, cc = tid & 127;
  const int n0 = g4 * 13, cnt13 = (g4 == 3) ? 12 : 13;

  // ---- phase A (fused): K=E@wk, V=E@wv, T1=E@fc_top, T2=E@wkp in ONE E pass ----
  {
    float aK[13], aV[13], aT1[13], aT2[13];
#pragma unroll
    for (int r = 0; r < 13; ++r) { aK[r] = 0.f; aV[r] = 0.f; aT1[r] = 0.f; aT2[r] = 0.f; }
    for (int i = 0; i < DD; i += 4) {
      const float k0 = wk[(i + 0) * DD + cc], k1 = wk[(i + 1) * DD + cc];
      const float k2 = wk[(i + 2) * DD + cc], k3 = wk[(i + 3) * DD + cc];
      const float v0 = wv[(i + 0) * DD + cc], v1 = wv[(i + 1) * DD + cc];
      const float v2 = wv[(i + 2) * DD + cc], v3 = wv[(i + 3) * DD + cc];
      const float f0 = fc_w[(i + 0) * DD + cc], f1 = fc_w[(i + 1) * DD + cc];
      const float f2 = fc_w[(i + 2) * DD + cc], f3 = fc_w[(i + 3) * DD + cc];
      const float p0 = wkp[(i + 0) * DD + cc], p1 = wkp[(i + 1) * DD + cc];
      const float p2 = wkp[(i + 2) * DD + cc], p3 = wkp[(i + 3) * DD + cc];
#pragma unroll
      for (int r = 0; r < 13; ++r) {
        if (r < cnt13) {
          const float4 e4 = *(const float4*)&qpoolL[(n0 + r) * DD + i];
          aK[r]  += e4.x * k0 + e4.y * k1 + e4.z * k2 + e4.w * k3;
          aV[r]  += e4.x * v0 + e4.y * v1 + e4.z * v2 + e4.w * v3;
          aT1[r] += e4.x * f0 + e4.y * f1 + e4.z * f2 + e4.w * f3;
          aT2[r] += e4.x * p0 + e4.y * p1 + e4.z * p2 + e4.w * p3;
        }
      }
    }
    // writes go to different buffers than the E being read; no barrier needed
#pragma unroll
    for (int r = 0; r < 13; ++r) {
      if (r < cnt13) {
        Ksh[(n0 + r) * RS + cc]   = aK[r];
        Vsh[(n0 + r) * RS + cc]   = aV[r];
        EQsh[(n0 + r) * RS + cc]  = aT1[r];
        KP2sh[(n0 + r) * RS + cc] = aT2[r];
      }
    }
  }
  __syncthreads();  // S3: T1/T2 complete

  // ---- phase B (fused, in place): EQ = T1@wq ; KP2 = T2@wo^T ----
  {
    float aEQ[13], aKP[13];
#pragma unroll
    for (int r = 0; r < 13; ++r) { aEQ[r] = 0.f; aKP[r] = 0.f; }
    for (int i = 0; i < DD; i += 4) {
      const float q0 = wq[(i + 0) * DD + cc], q1 = wq[(i + 1) * DD + cc];
      const float q2 = wq[(i + 2) * DD + cc], q3 = wq[(i + 3) * DD + cc];
      const float4 w4 = *(const float4*)&wo[cc * DD + i];
#pragma unroll
      for (int r = 0; r < 13; ++r) {
        if (r < cnt13) {
          const float4 t1 = *(const float4*)&EQsh[(n0 + r) * RS + i];
          const float4 t2 = *(const float4*)&KP2sh[(n0 + r) * RS + i];
          aEQ[r] += t1.x * q0 + t1.y * q1 + t1.z * q2 + t1.w * q3;
          aKP[r] += dot4(t2, w4);
        }
      }
    }
    __syncthreads();  // S4: all reads done before in-place overwrite
#pragma unroll
    for (int r = 0; r < 13; ++r) {
      if (r < cnt13) {
        EQsh[(n0 + r) * RS + cc]  = aEQ[r];
        KP2sh[(n0 + r) * RS + cc] = aKP[r];
      }
    }
  }
  __syncthreads();  // S5

  // ---- phase C: serial pool chain (pools into qpoolL), then parallel @wq ----
  {
    const int i0 = g4 * 32;
    float wf[32];
#pragma unroll
    for (int i = 0; i < 32; ++i) wf[i] = fc1[(i0 + i) * DD + cc];
    for (int t = 0; t < ns; ++t) {
      float s = 0.f;
#pragma unroll
      for (int i = 0; i < 32; ++i) s += poolL[i0 + i] * wf[i];
      partF[tid] = s;
      __syncthreads();
      if (tid < 128) {
        const float v = partF[tid] + partF[tid + 128] + partF[tid + 256] + partF[tid + 384];
        qpoolL[t * DD + tid] = v;   // pool_{t+1}
        poolL[tid] = v;
      }
      __syncthreads();
    }
    // qpool[t] = pools[t] @ wq, in place, chunked rows per group
    const int qch = (ns + 3) >> 2;
    const int r0 = g4 * qch;
    const int rcnt = (ns - r0 < qch) ? (ns - r0) : qch;  // may be <= 0
    float acc[16];
#pragma unroll
    for (int r = 0; r < 16; ++r) acc[r] = 0.f;
    for (int i = 0; i < DD; i += 4) {
      const float q0 = wq[(i + 0) * DD + cc], q1 = wq[(i + 1) * DD + cc];
      const float q2 = wq[(i + 2) * DD + cc], q3 = wq[(i + 3) * DD + cc];
#pragma unroll
      for (int r = 0; r < 16; ++r) {
        if (r < rcnt) {
          const float4 p4 = *(const float4*)&qpoolL[(r0 + r) * DD + i];
          acc[r] += p4.x * q0 + p4.y * q1 + p4.z * q2 + p4.w * q3;
        }
      }
    }
    __syncthreads();  // reads done before in-place overwrite
#pragma unroll
    for (int r = 0; r < 16; ++r)
      if (r < rcnt) qpoolL[(r0 + r) * DD + cc] = acc[r];
    __syncthreads();
  }

  // ---- decode: 3 barriers/step ----
  int m1 = 0;
  float dynr = cap0;
  float lpacc0 = 0.f;   // wave0 lane0: sum logits[best]
  float lpacc1 = 0.f;   // wave1 lane0: sum LSE

  for (int t = 0; t < ns; ++t) {
    // X: wave w = head w; lane l = node l. QK + softmax + PV.
    {
      const int hbase = w * 16;
      const int best = bestS;
      const float dyn = dynS;
      const float dep = depotS;
      const unsigned long long M1 = sM1;
      const bool maskedl =
          (l == 0) ? (dep > 0.f)
          : (l < NN ? ((((M1 >> l) & 1ull) != 0ull) || (dem_l > dyn)) : true);
      float4 qv0, qv1, qv2, qv3;
      {
        const float4* eq = (const float4*)&EQsh[best * RS + hbase];
        const float4* wr = (const float4*)&wrowL[hbase];
        const float4* qp = (const float4*)&qpoolL[t * DD + hbase];
        const float4 e0 = eq[0], e1 = eq[1], e2 = eq[2], e3 = eq[3];
        const float4 r0 = wr[0], r1 = wr[1], r2 = wr[2], r3 = wr[3];
        const float4 p0 = qp[0], p1 = qp[1], p2 = qp[2], p3 = qp[3];
        qv0.x = e0.x + dyn * r0.x + p0.x; qv0.y = e0.y + dyn * r0.y + p0.y;
        qv0.z = e0.z + dyn * r0.z + p0.z; qv0.w = e0.w + dyn * r0.w + p0.w;
        qv1.x = e1.x + dyn * r1.x + p1.x; qv1.y = e1.y + dyn * r1.y + p1.y;
        qv1.z = e1.z + dyn * r1.z + p1.z; qv1.w = e1.w + dyn * r1.w + p1.w;
        qv2.x = e2.x + dyn * r2.x + p2.x; qv2.y = e2.y + dyn * r2.y + p2.y;
        qv2.z = e2.z + dyn * r2.z + p2.z; qv2.w = e2.w + dyn * r2.w + p2.w;
        qv3.x = e3.x + dyn * r3.x + p3.x; qv3.y = e3.y + dyn * r3.y + p3.y;
        qv3.z = e3.z + dyn * r3.z + p3.z; qv3.w = e3.w + dyn * r3.w + p3.w;
      }
      float u1 = NINF;
      if (l < NN && !maskedl) {
        const float4* kr = (const float4*)&Ksh[l * RS + hbase];
        u1 = 0.25f * ((dot4(kr[0], qv0) + dot4(kr[1], qv1)) +
                      (dot4(kr[2], qv2) + dot4(kr[3], qv3)));
      }
      float mx = u1;
#pragma unroll
      for (int o = 32; o; o >>= 1) mx = fmaxf(mx, __shfl_xor(mx, o));
      const float e = (u1 > NINF) ? expf(u1 - mx) : 0.f;
      float S = e;
#pragma unroll
      for (int o = 32; o; o >>= 1) S += __shfl_xor(S, o);
      if (l < NVR) uL[w * NVR + l] = e;   // lane 51 writes 0 (pad)
      asm volatile("s_waitcnt lgkmcnt(0)" ::: "memory");
      __builtin_amdgcn_sched_barrier(0);
      // PV: lane -> (res = n mod 4, dlo); a_n via LDS broadcast reads
      const int res = l >> 4, dlo = l & 15;
      float acc = 0.f;
#pragma unroll
      for (int jj = 0; jj < 13; ++jj) {
        const int n = 4 * jj + res;            // max 51 (V row 51 zero)
        acc += uL[w * NVR + n] * Vsh[n * RS + hbase + dlo];
      }
      acc += __shfl_xor(acc, 16);
      acc += __shfl_xor(acc, 32);
      if (res == 0) gL[hbase + dlo] = acc / S;
    }
    __syncthreads();
    // Y: waves 0-6: comp/logits/pert per node (8-lane groups); wave 7: gumbel(t+1)
    {
      if (w < 7) {
        const int gn = tid >> 3, li = tid & 7;
        if (gn < NN) {
          const float4* kp = (const float4*)&KP2sh[gn * RS + li * 16];
          const float4* gg = (const float4*)&gL[li * 16];
          float p = (dot4(kp[0], gg[0]) + dot4(kp[1], gg[1])) +
                    (dot4(kp[2], gg[2]) + dot4(kp[3], gg[3]));
          p += __shfl_xor(p, 1, 8);
          p += __shfl_xor(p, 2, 8);
          p += __shfl_xor(p, 4, 8);
          if (li == 0) {
            const float comp = p * 0.08838834764831845f;  // 128^-0.5
            const float lg = (10.f * tanhf(comp)) / Tval;
            const bool maskedn =
                (gn == 0) ? (depotS > 0.f)
                          : ((((sM1 >> gn) & 1ull) != 0ull) || (demL[gn] > dynS));
            const float lgv = maskedn ? NINF : lg;
            logitsL[gn] = lgv;
            pertL[gn] = greedy ? lgv : (lgv + pgumL[t & 1][gn]);
          }
        }
      } else {
        if (!greedy && l < NN && t + 1 < ns)
          pgumL[(t + 1) & 1][l] =
              gumbel_from(keysL[2 * (t + 1)], keysL[2 * (t + 1) + 1],
                          (unsigned)(b * NN + l));
      }
    }
    __syncthreads();
    // Z: wave0 = argmax + state; wave1 = LSE (parallel)
    {
      if (w == 0) {
        const float pv = (l < NN) ? pertL[l] : NINF;
        float vmax = pv;
#pragma unroll
        for (int o = 32; o; o >>= 1) vmax = fmaxf(vmax, __shfl_xor(vmax, o));
        const unsigned long long Meq = __ballot(pv == vmax);
        const int best = __ffsll(Meq) - 1;     // first max = jnp.argmax tie-break
        if (l == best) m1 = 1;
        const unsigned long long M = __ballot(m1 != 0);
        const int cntv = (int)__popcll(M & ~1ull);
        const float dem_b = __shfl(dem_l, best);
        dynr = (best == 0) ? cap0 : (dynr - dem_b);
        float depot = (best == 0) ? 1.f : 0.f;
        if (cntv >= NN - 1) depot = 0.f;
        if (l == 0) {
          bestS = best; dynS = dynr; depotS = depot; sM1 = M;
          lpacc0 += logitsL[best];
          out[b * ns + t] = (float)best;
        }
      } else if (w == 1) {
        const float lv = (l < NN) ? logitsL[l] : NINF;
        float mm = lv;
#pragma unroll
        for (int o = 32; o; o >>= 1) mm = fmaxf(mm, __shfl_xor(mm, o));
        float ee = (lv > NINF) ? expf(lv - mm) : 0.f;
#pragma unroll
        for (int o = 32; o; o >>= 1) ee += __shfl_xor(ee, o);
        if (l == 0) lpacc1 += mm + logf(ee);
      }
    }
    __syncthreads();
  }
  if (tid == 0)  lpW0s = lpacc0;
  if (tid == 64) lpW1s = lpacc1;
  __syncthreads();
  if (tid == 0) out[Bn * ns + b] = lpW0s - lpW1s;
}

extern "C" void kernel_launch(void* const* d_in, const int* in_sizes, int n_in,
                              void* d_out, int out_size, void* d_ws, size_t ws_size,
                              hipStream_t stream) {
  const float* enc    = (const float*)d_in[0];
  const float* pool   = (const float*)d_in[1];
  const float* cap    = (const float*)d_in[2];
  const float* dem    = (const float*)d_in[3];
  const float* fc_w   = (const float*)d_in[4];
  const float* fc1_w  = (const float*)d_in[5];
  const float* wq     = (const float*)d_in[6];
  const float* wk     = (const float*)d_in[7];
  const float* wv     = (const float*)d_in[8];
  const float* wo     = (const float*)d_in[9];
  const float* wkp    = (const float*)d_in[10];
  const float* Tp     = (const float*)d_in[11];
  const int*   nsp    = (const int*)d_in[12];
  const int*   greedy = (const int*)d_in[14];
  float* out = (float*)d_out;

  const int B = in_sizes[1] / DD;  // pool is (B,128)

  hipLaunchKernelGGL(decode_kernel, dim3(B), dim3(512), 0, stream,
                     enc, pool, cap, dem, fc_w, fc1_w, wq, wk, wv, wo, wkp,
                     Tp, nsp, greedy, out);
}

// Round 9
// 223.988 us; speedup vs baseline: 1.1358x; 1.1358x over previous
//
#include <hip/hip_runtime.h>

#define NN 51
#define DD 128
#define RS 132    // LDS row stride (words)
#define NT 64
#define NINFF (-__builtin_inff())

__device__ __forceinline__ float dot4(const float4 a, const float4 b) {
  return a.x * b.x + a.y * b.y + a.z * b.z + a.w * b.w;
}

// ---- DPP cross-lane (VALU pipe, no LDS) ----
template<int CTRL>
__device__ __forceinline__ float dppf(float x, float idf) {
  return __int_as_float(__builtin_amdgcn_update_dpp(
      __float_as_int(idf), __float_as_int(x), CTRL, 0xf, 0xf, false));
}
__device__ __forceinline__ float bcast63(float x) {
  return __int_as_float(__builtin_amdgcn_readlane(__float_as_int(x), 63));
}
__device__ __forceinline__ float wave_max_b(float x) {
  x = fmaxf(x, dppf<0x111>(x, NINFF));  // row_shr:1
  x = fmaxf(x, dppf<0x112>(x, NINFF));  // row_shr:2
  x = fmaxf(x, dppf<0x114>(x, NINFF));  // row_shr:4
  x = fmaxf(x, dppf<0x118>(x, NINFF));  // row_shr:8
  x = fmaxf(x, dppf<0x142>(x, NINFF));  // row_bcast:15
  x = fmaxf(x, dppf<0x143>(x, NINFF));  // row_bcast:31
  return bcast63(x);
}
__device__ __forceinline__ float wave_sum_b(float x) {
  x += dppf<0x111>(x, 0.f);
  x += dppf<0x112>(x, 0.f);
  x += dppf<0x114>(x, 0.f);
  x += dppf<0x118>(x, 0.f);
  x += dppf<0x142>(x, 0.f);
  x += dppf<0x143>(x, 0.f);
  return bcast63(x);
}
__device__ __forceinline__ float row16_sum(float x) {  // totals in lanes 15/31/47/63
  x += dppf<0x111>(x, 0.f);
  x += dppf<0x112>(x, 0.f);
  x += dppf<0x114>(x, 0.f);
  x += dppf<0x118>(x, 0.f);
  return x;
}
__device__ __forceinline__ float grp8_sum(float x) {   // total in ALL lanes of each 8-group
  x += dppf<0xB1>(x, 0.f);   // quad_perm xor1 -> pair sums
  x += dppf<0x4E>(x, 0.f);   // quad_perm xor2 -> quad total (all 4 lanes)
  x += dppf<0x141>(x, 0.f);  // ROW_HALF_MIRROR: partner quad's total (quad0<->1, 2<->3)
  return x;
}

// JAX threefry2x32 (20 rounds), exact.
__device__ __forceinline__ void tf2x32(unsigned k0, unsigned k1, unsigned &x0, unsigned &x1) {
  const unsigned ks2 = k0 ^ k1 ^ 0x1BD11BDAu;
  const unsigned ka[5] = {k1, ks2, k0, k1, ks2};
  const unsigned kb[5] = {ks2 + 1u, k0 + 2u, k1 + 3u, ks2 + 4u, k0 + 5u};
  x0 += k0; x1 += k1;
#pragma unroll
  for (int g = 0; g < 5; ++g) {
    const int r0 = (g & 1) ? 17 : 13;
    const int r1 = (g & 1) ? 29 : 15;
    const int r2 = (g & 1) ? 16 : 26;
    const int r3 = (g & 1) ? 24 : 6;
    x0 += x1; x1 = (x1 << r0) | (x1 >> (32 - r0)); x1 ^= x0;
    x0 += x1; x1 = (x1 << r1) | (x1 >> (32 - r1)); x1 ^= x0;
    x0 += x1; x1 = (x1 << r2) | (x1 >> (32 - r2)); x1 ^= x0;
    x0 += x1; x1 = (x1 << r3) | (x1 >> (32 - r3)); x1 ^= x0;
    x0 += ka[g]; x1 += kb[g];
  }
}

__device__ __forceinline__ float gumbel_from(unsigned k0, unsigned k1, unsigned ctr) {
  unsigned x0 = 0u, x1 = ctr;
  tf2x32(k0, k1, x0, x1);
  const unsigned bits = x0 ^ x1;
  const float fl = __uint_as_float((bits >> 9) | 0x3f800000u) - 1.0f;
  const float TINY = 1.17549435e-38f;
  const float uu = fmaxf(TINY, fl + TINY);
  return -logf(-logf(uu));
}

__global__ __launch_bounds__(512, 1) void decode_kernel(
    const float* __restrict__ enc, const float* __restrict__ pool_in,
    const float* __restrict__ cap_p, const float* __restrict__ demand,
    const float* __restrict__ fc_w, const float* __restrict__ fc1,
    const float* __restrict__ wq, const float* __restrict__ wk,
    const float* __restrict__ wv, const float* __restrict__ wo,
    const float* __restrict__ wkp, const float* __restrict__ T_p,
    const int* __restrict__ ns_p, const int* __restrict__ greedy_p,
    float* __restrict__ out) {
  __shared__ __align__(16) float Ksh[NN * RS];
  __shared__ __align__(16) float Vsh[64 * RS];     // rows 51..63 zero
  __shared__ __align__(16) float KP2sh[NN * RS];
  __shared__ __align__(16) float EQsh[NN * RS];
  __shared__ __align__(16) float qpoolL[NT * DD];  // staged enc -> pools -> qpool[t]
  __shared__ __align__(16) float uL[8 * 64];       // softmax numerators e (64-padded)
  __shared__ __align__(16) float gL[DD];
  __shared__ __align__(16) float qLbuf[DD];
  __shared__ __align__(16) float poolL[DD];
  __shared__ __align__(16) float wrowL[DD];
  __shared__ __align__(16) float partF[512];
  __shared__ __align__(16) float stateF4[4];       // {dyn, depot, bestF, 0}
  __shared__ __align__(8)  unsigned stateM2[2];    // visited mask
  __shared__ float demL[NN];
  __shared__ float logitsL[NN], pertL[NN];
  __shared__ float pgumL[2][NN];
  __shared__ unsigned keysL[2 * NT];
  __shared__ float lp0s, lp1s;

  const int b = blockIdx.x, tid = threadIdx.x;
  const int Bn = gridDim.x;
  const int w = tid >> 6, l = tid & 63;
  int ns = *ns_p; if (ns > NT) ns = NT;
  const int greedy = *greedy_p;
  const float Tval = *T_p;
  const float cap0 = *cap_p;

  // ---- stage ----
  {
    const float4* src = (const float4*)(enc + (size_t)b * NN * DD);
    float4* dst = (float4*)qpoolL;
    for (int e = tid; e < NN * DD / 4; e += 512) dst[e] = src[e];
  }
  if (tid < 128) poolL[tid] = pool_in[b * DD + tid];
  for (int e = tid; e < 13 * RS; e += 512) Vsh[51 * RS + e] = 0.f;  // V pad rows
  if (tid < NN)  demL[tid] = demand[b * NN + tid];
  if (tid < ns) {
    unsigned a0 = 0u, a1 = 0u;
    tf2x32(0u, 1234u, a0, a1);
    unsigned x0 = 0u, x1 = (unsigned)tid;
    tf2x32(a0, a1, x0, x1);
    keysL[2 * tid] = x0; keysL[2 * tid + 1] = x1;
  }
  __syncthreads();

  float dem_l = (l < NN) ? demL[l] : 0.f;

  // gumbel(0) (wave 7)
  if (!greedy && tid >= 448) {
    const int gl = tid - 448;
    if (gl < NN)
      pgumL[0][gl] = gumbel_from(keysL[0], keysL[1], (unsigned)(b * NN + gl));
  }
  // wrow partials
  {
    const int c = tid & 127, qd = tid >> 7;
    const float* fr = fc_w + 128 * DD;
    float s = 0.f;
    for (int j = qd * 32; j < qd * 32 + 32; ++j) s += fr[j] * wq[j * DD + c];
    partF[tid] = s;
  }
  __syncthreads();
  if (tid < 128)
    wrowL[tid] = partF[tid] + partF[tid + 128] + partF[tid + 256] + partF[tid + 384];

  const int g4 = tid >> 7, cc = tid & 127;
  const int n0 = g4 * 13, cnt13 = (g4 == 3) ? 12 : 13;

  // ---- phase A (fused): K, V, T1, T2 in one E pass ----
  {
    float aK[13], aV[13], aT1[13], aT2[13];
#pragma unroll
    for (int r = 0; r < 13; ++r) { aK[r] = 0.f; aV[r] = 0.f; aT1[r] = 0.f; aT2[r] = 0.f; }
    for (int i = 0; i < DD; i += 4) {
      const float k0 = wk[(i + 0) * DD + cc], k1 = wk[(i + 1) * DD + cc];
      const float k2 = wk[(i + 2) * DD + cc], k3 = wk[(i + 3) * DD + cc];
      const float v0 = wv[(i + 0) * DD + cc], v1 = wv[(i + 1) * DD + cc];
      const float v2 = wv[(i + 2) * DD + cc], v3 = wv[(i + 3) * DD + cc];
      const float f0 = fc_w[(i + 0) * DD + cc], f1 = fc_w[(i + 1) * DD + cc];
      const float f2 = fc_w[(i + 2) * DD + cc], f3 = fc_w[(i + 3) * DD + cc];
      const float p0 = wkp[(i + 0) * DD + cc], p1 = wkp[(i + 1) * DD + cc];
      const float p2 = wkp[(i + 2) * DD + cc], p3 = wkp[(i + 3) * DD + cc];
#pragma unroll
      for (int r = 0; r < 13; ++r) {
        if (r < cnt13) {
          const float4 e4 = *(const float4*)&qpoolL[(n0 + r) * DD + i];
          aK[r]  += e4.x * k0 + e4.y * k1 + e4.z * k2 + e4.w * k3;
          aV[r]  += e4.x * v0 + e4.y * v1 + e4.z * v2 + e4.w * v3;
          aT1[r] += e4.x * f0 + e4.y * f1 + e4.z * f2 + e4.w * f3;
          aT2[r] += e4.x * p0 + e4.y * p1 + e4.z * p2 + e4.w * p3;
        }
      }
    }
#pragma unroll
    for (int r = 0; r < 13; ++r) {
      if (r < cnt13) {
        Ksh[(n0 + r) * RS + cc]   = aK[r];
        Vsh[(n0 + r) * RS + cc]   = aV[r];
        EQsh[(n0 + r) * RS + cc]  = aT1[r];
        KP2sh[(n0 + r) * RS + cc] = aT2[r];
      }
    }
  }
  __syncthreads();

  // ---- phase B (fused, in place): EQ = T1@wq ; KP2 = T2@wo^T ----
  {
    float aEQ[13], aKP[13];
#pragma unroll
    for (int r = 0; r < 13; ++r) { aEQ[r] = 0.f; aKP[r] = 0.f; }
    for (int i = 0; i < DD; i += 4) {
      const float q0 = wq[(i + 0) * DD + cc], q1 = wq[(i + 1) * DD + cc];
      const float q2 = wq[(i + 2) * DD + cc], q3 = wq[(i + 3) * DD + cc];
      const float4 w4 = *(const float4*)&wo[cc * DD + i];
#pragma unroll
      for (int r = 0; r < 13; ++r) {
        if (r < cnt13) {
          const float4 t1 = *(const float4*)&EQsh[(n0 + r) * RS + i];
          const float4 t2 = *(const float4*)&KP2sh[(n0 + r) * RS + i];
          aEQ[r] += t1.x * q0 + t1.y * q1 + t1.z * q2 + t1.w * q3;
          aKP[r] += dot4(t2, w4);
        }
      }
    }
    __syncthreads();
#pragma unroll
    for (int r = 0; r < 13; ++r) {
      if (r < cnt13) {
        EQsh[(n0 + r) * RS + cc]  = aEQ[r];
        KP2sh[(n0 + r) * RS + cc] = aKP[r];
      }
    }
  }
  __syncthreads();

  // ---- phase C: serial pool chain, then parallel @wq in place ----
  {
    const int i0 = g4 * 32;
    float wf[32];
#pragma unroll
    for (int i = 0; i < 32; ++i) wf[i] = fc1[(i0 + i) * DD + cc];
    for (int t = 0; t < ns; ++t) {
      float s = 0.f;
#pragma unroll
      for (int i = 0; i < 32; ++i) s += poolL[i0 + i] * wf[i];
      partF[tid] = s;
      __syncthreads();
      if (tid < 128) {
        const float v = partF[tid] + partF[tid + 128] + partF[tid + 256] + partF[tid + 384];
        qpoolL[t * DD + tid] = v;
        poolL[tid] = v;
      }
      __syncthreads();
    }
    const int qch = (ns + 3) >> 2;
    const int r0 = g4 * qch;
    const int rcnt = (ns - r0 < qch) ? (ns - r0) : qch;
    float acc[16];
#pragma unroll
    for (int r = 0; r < 16; ++r) acc[r] = 0.f;
    for (int i = 0; i < DD; i += 4) {
      const float q0 = wq[(i + 0) * DD + cc], q1 = wq[(i + 1) * DD + cc];
      const float q2 = wq[(i + 2) * DD + cc], q3 = wq[(i + 3) * DD + cc];
#pragma unroll
      for (int r = 0; r < 16; ++r) {
        if (r < rcnt) {
          const float4 p4 = *(const float4*)&qpoolL[(r0 + r) * DD + i];
          acc[r] += p4.x * q0 + p4.y * q1 + p4.z * q2 + p4.w * q3;
        }
      }
    }
    __syncthreads();
#pragma unroll
    for (int r = 0; r < 16; ++r)
      if (r < rcnt) qpoolL[(r0 + r) * DD + cc] = acc[r];
  }
  __syncthreads();

  // ---- pre-loop: wave0 regs + initial state + initial qL ----
  int m1 = 0;
  float dynr = cap0, lpacc0 = 0.f, lpacc1 = 0.f;
  float2 wr2 = {0.f, 0.f};
  if (w == 0) {
    wr2 = *(const float2*)&wrowL[2 * l];
    const float2 eq2 = *(const float2*)&EQsh[2 * l];          // best=0
    const float2 qp2 = *(const float2*)&qpoolL[2 * l];        // t=0
    float2 qv;
    qv.x = eq2.x + cap0 * wr2.x + qp2.x;
    qv.y = eq2.y + cap0 * wr2.y + qp2.y;
    *(float2*)&qLbuf[2 * l] = qv;
    if (l == 0) {
      stateF4[0] = cap0; stateF4[1] = 1.f; stateF4[2] = 0.f; stateF4[3] = 0.f;
      stateM2[0] = 1u; stateM2[1] = 0u;
    }
  }
  __syncthreads();

  // ---- decode: 3 barriers/step, DPP reductions ----
  for (int t = 0; t < ns; ++t) {
    // X: wave w = head w; QK + softmax + PV
    {
      const float4 sF = *(const float4*)stateF4;
      const uint2  sM = *(const uint2*)stateM2;
      const unsigned long long M1 =
          ((unsigned long long)sM.y << 32) | (unsigned long long)sM.x;
      const float dyn = sF.x, dep = sF.y;
      const bool maskedl =
          (l == 0) ? (dep > 0.f)
          : (l < NN ? ((((M1 >> l) & 1ull) != 0ull) || (dem_l > dyn)) : true);
      const float4* qr = (const float4*)&qLbuf[w * 16];
      const float4 q0 = qr[0], q1 = qr[1], q2 = qr[2], q3 = qr[3];
      float u1 = NINFF;
      if (l < NN && !maskedl) {
        const float4* kr = (const float4*)&Ksh[l * RS + w * 16];
        u1 = 0.25f * ((dot4(kr[0], q0) + dot4(kr[1], q1)) +
                      (dot4(kr[2], q2) + dot4(kr[3], q3)));
      }
      const float mx = wave_max_b(u1);
      const float e = (u1 > NINFF) ? expf(u1 - mx) : 0.f;
      const float S = wave_sum_b(e);
      uL[w * 64 + l] = e;   // all 64 lanes (pads are 0)
      asm volatile("s_waitcnt lgkmcnt(0)" ::: "memory");
      __builtin_amdgcn_sched_barrier(0);
      // PV: row = dim-quad (l>>4), col index nn0 = l&15; n = nn0 + 16j
      const int nn0 = l & 15, dq = l >> 4;
      float ax = 0.f, ay = 0.f, az = 0.f, aw = 0.f;
#pragma unroll
      for (int j = 0; j < 4; ++j) {
        const int n = nn0 + 16 * j;
        const float a = uL[w * 64 + n];
        const float4 v4 = *(const float4*)&Vsh[n * RS + w * 16 + dq * 4];
        ax += a * v4.x; ay += a * v4.y; az += a * v4.z; aw += a * v4.w;
      }
      ax = row16_sum(ax); ay = row16_sum(ay);
      az = row16_sum(az); aw = row16_sum(aw);
      if (nn0 == 15) {
        float4 gv;
        gv.x = ax / S; gv.y = ay / S; gv.z = az / S; gv.w = aw / S;
        *(float4*)&gL[w * 16 + dq * 4] = gv;
      }
    }
    __syncthreads();
    // Y: waves 0-6: comp/logits/pert (8-lane groups); wave 7: gumbel(t+1)
    if (w < 7) {
      const int gn = tid >> 3, li = tid & 7;
      float p = 0.f;
      if (gn < NN) {
        const float4* kp = (const float4*)&KP2sh[gn * RS + li * 16];
        const float4* gg = (const float4*)&gL[li * 16];
        p = (dot4(kp[0], gg[0]) + dot4(kp[1], gg[1])) +
            (dot4(kp[2], gg[2]) + dot4(kp[3], gg[3]));
      }
      p = grp8_sum(p);
      if (gn < NN && li == 0) {
        const float comp = p * 0.08838834764831845f;  // 128^-0.5
        const float lg = (10.f * tanhf(comp)) / Tval;
        const float4 sF = *(const float4*)stateF4;
        const uint2  sM = *(const uint2*)stateM2;
        const unsigned long long M1 =
            ((unsigned long long)sM.y << 32) | (unsigned long long)sM.x;
        const bool maskedn =
            (gn == 0) ? (sF.y > 0.f)
                      : ((((M1 >> gn) & 1ull) != 0ull) || (demL[gn] > sF.x));
        const float lgv = maskedn ? NINFF : lg;
        logitsL[gn] = lgv;
        pertL[gn] = greedy ? lgv : (lgv + pgumL[t & 1][gn]);
      }
    } else {
      if (!greedy && l < NN && t + 1 < ns)
        pgumL[(t + 1) & 1][l] =
            gumbel_from(keysL[2 * (t + 1)], keysL[2 * (t + 1) + 1],
                        (unsigned)(b * NN + l));
    }
    __syncthreads();
    // Z: wave0 = argmax + state + next-qL ; wave1 = LSE
    if (w == 0) {
      const float pv  = (l < NN) ? pertL[l]   : NINFF;
      const float lgv = (l < NN) ? logitsL[l] : NINFF;
      const float vmax = wave_max_b(pv);
      const unsigned long long Meq = __ballot(pv == vmax);
      const int best = __ffsll((unsigned long long)Meq) - 1;  // first max
      if (l == best) m1 = 1;
      const unsigned long long M = __ballot(m1 != 0);
      const int cntv = (int)__popcll(M & ~1ull);
      const float dem_b =
          __int_as_float(__builtin_amdgcn_readlane(__float_as_int(dem_l), best));
      dynr = (best == 0) ? cap0 : (dynr - dem_b);
      float depot = (best == 0) ? 1.f : 0.f;
      if (cntv >= NN - 1) depot = 0.f;
      lpacc0 += __int_as_float(__builtin_amdgcn_readlane(__float_as_int(lgv), best));
      if (l == 0) {
        stateF4[0] = dynr; stateF4[1] = depot;
        stateF4[2] = (float)best; stateF4[3] = 0.f;
        stateM2[0] = (unsigned)M; stateM2[1] = (unsigned)(M >> 32);
        out[b * ns + t] = (float)best;
      }
      const int qidx = (t + 1 < ns) ? (t + 1) : 0;
      const float2 eq2 = *(const float2*)&EQsh[best * RS + 2 * l];
      const float2 qp2 = *(const float2*)&qpoolL[qidx * DD + 2 * l];
      float2 qv;
      qv.x = eq2.x + dynr * wr2.x + qp2.x;
      qv.y = eq2.y + dynr * wr2.y + qp2.y;
      *(float2*)&qLbuf[2 * l] = qv;
    } else if (w == 1) {
      const float lv = (l < NN) ? logitsL[l] : NINFF;
      const float mm = wave_max_b(lv);
      const float ee = wave_sum_b((lv > NINFF) ? expf(lv - mm) : 0.f);
      lpacc1 += mm + logf(ee);
    }
    __syncthreads();
  }
  if (tid == 0)  lp0s = lpacc0;
  if (tid == 64) lp1s = lpacc1;
  __syncthreads();
  if (tid == 0) out[Bn * ns + b] = lp0s - lp1s;
}

extern "C" void kernel_launch(void* const* d_in, const int* in_sizes, int n_in,
                              void* d_out, int out_size, void* d_ws, size_t ws_size,
                              hipStream_t stream) {
  const float* enc    = (const float*)d_in[0];
  const float* pool   = (const float*)d_in[1];
  const float* cap    = (const float*)d_in[2];
  const float* dem    = (const float*)d_in[3];
  const float* fc_w   = (const float*)d_in[4];
  const float* fc1_w  = (const float*)d_in[5];
  const float* wq     = (const float*)d_in[6];
  const float* wk     = (const float*)d_in[7];
  const float* wv     = (const float*)d_in[8];
  const float* wo     = (const float*)d_in[9];
  const float* wkp    = (const float*)d_in[10];
  const float* Tp     = (const float*)d_in[11];
  const int*   nsp    = (const int*)d_in[12];
  const int*   greedy = (const int*)d_in[14];
  float* out = (float*)d_out;

  const int B = in_sizes[1] / DD;  // pool is (B,128)

  hipLaunchKernelGGL(decode_kernel, dim3(B), dim3(512), 0, stream,
                     enc, pool, cap, dem, fc_w, fc1_w, wq, wk, wv, wo, wkp,
                     Tp, nsp, greedy, out);
}

// Round 10
// 206.073 us; speedup vs baseline: 1.2345x; 1.0869x over previous
//
#include <hip/hip_runtime.h>

#define NN 51
#define DD 128
#define RS 132    // LDS row stride (words)
#define NT 64
#define NINFF (-__builtin_inff())

__device__ __forceinline__ float dot4(const float4 a, const float4 b) {
  return a.x * b.x + a.y * b.y + a.z * b.z + a.w * b.w;
}

// ---- DPP cross-lane (VALU pipe) ----
template<int CTRL>
__device__ __forceinline__ float dppf(float x, float idf) {
  return __int_as_float(__builtin_amdgcn_update_dpp(
      __float_as_int(idf), __float_as_int(x), CTRL, 0xf, 0xf, false));
}
__device__ __forceinline__ float readlanef(float x, int lane) {
  return __int_as_float(__builtin_amdgcn_readlane(__float_as_int(x), lane));
}
__device__ __forceinline__ float bcast63(float x) { return readlanef(x, 63); }
__device__ __forceinline__ float wave_max_b(float x) {
  x = fmaxf(x, dppf<0x111>(x, NINFF));
  x = fmaxf(x, dppf<0x112>(x, NINFF));
  x = fmaxf(x, dppf<0x114>(x, NINFF));
  x = fmaxf(x, dppf<0x118>(x, NINFF));
  x = fmaxf(x, dppf<0x142>(x, NINFF));
  x = fmaxf(x, dppf<0x143>(x, NINFF));
  return bcast63(x);
}
__device__ __forceinline__ float wave_sum_b(float x) {
  x += dppf<0x111>(x, 0.f);
  x += dppf<0x112>(x, 0.f);
  x += dppf<0x114>(x, 0.f);
  x += dppf<0x118>(x, 0.f);
  x += dppf<0x142>(x, 0.f);
  x += dppf<0x143>(x, 0.f);
  return bcast63(x);
}
__device__ __forceinline__ float row16_sum(float x) {  // totals at lanes 15/31/47/63
  x += dppf<0x111>(x, 0.f);
  x += dppf<0x112>(x, 0.f);
  x += dppf<0x114>(x, 0.f);
  x += dppf<0x118>(x, 0.f);
  return x;
}
__device__ __forceinline__ float quad_sum(float x) {   // total in all 4 lanes of quad
  x += dppf<0xB1>(x, 0.f);   // quad_perm [1,0,3,2]
  x += dppf<0x4E>(x, 0.f);   // quad_perm [2,3,0,1]
  return x;
}

// JAX threefry2x32 (20 rounds), exact.
__device__ __forceinline__ void tf2x32(unsigned k0, unsigned k1, unsigned &x0, unsigned &x1) {
  const unsigned ks2 = k0 ^ k1 ^ 0x1BD11BDAu;
  const unsigned ka[5] = {k1, ks2, k0, k1, ks2};
  const unsigned kb[5] = {ks2 + 1u, k0 + 2u, k1 + 3u, ks2 + 4u, k0 + 5u};
  x0 += k0; x1 += k1;
#pragma unroll
  for (int g = 0; g < 5; ++g) {
    const int r0 = (g & 1) ? 17 : 13;
    const int r1 = (g & 1) ? 29 : 15;
    const int r2 = (g & 1) ? 16 : 26;
    const int r3 = (g & 1) ? 24 : 6;
    x0 += x1; x1 = (x1 << r0) | (x1 >> (32 - r0)); x1 ^= x0;
    x0 += x1; x1 = (x1 << r1) | (x1 >> (32 - r1)); x1 ^= x0;
    x0 += x1; x1 = (x1 << r2) | (x1 >> (32 - r2)); x1 ^= x0;
    x0 += x1; x1 = (x1 << r3) | (x1 >> (32 - r3)); x1 ^= x0;
    x0 += ka[g]; x1 += kb[g];
  }
}

__device__ __forceinline__ float gumbel_from(unsigned k0, unsigned k1, unsigned ctr) {
  unsigned x0 = 0u, x1 = ctr;
  tf2x32(k0, k1, x0, x1);
  const unsigned bits = x0 ^ x1;
  const float fl = __uint_as_float((bits >> 9) | 0x3f800000u) - 1.0f;
  const float TINY = 1.17549435e-38f;
  const float uu = fmaxf(TINY, fl + TINY);
  return -logf(-logf(uu));
}

__global__ __launch_bounds__(512, 1) void decode_kernel(
    const float* __restrict__ enc, const float* __restrict__ pool_in,
    const float* __restrict__ cap_p, const float* __restrict__ demand,
    const float* __restrict__ fc_w, const float* __restrict__ fc1,
    const float* __restrict__ wq, const float* __restrict__ wk,
    const float* __restrict__ wv, const float* __restrict__ wo,
    const float* __restrict__ wkp, const float* __restrict__ T_p,
    const int* __restrict__ ns_p, const int* __restrict__ greedy_p,
    float* __restrict__ out) {
  __shared__ __align__(16) float Ksh[NN * RS];
  __shared__ __align__(16) float Vsh[64 * RS];     // rows 51..63 zero
  __shared__ __align__(16) float KP2sh[NN * RS];
  __shared__ __align__(16) float EQsh[NN * RS];
  __shared__ __align__(16) float qpoolL[NT * DD];  // staged enc -> pools -> qpool[t]
  __shared__ __align__(16) float uL[8 * 64];       // softmax numerators (wave-private rows)
  __shared__ __align__(16) float pcb2[2][8 * 64];  // comp partials, double-buffered
  __shared__ __align__(16) float poolB[2][DD];     // pool chain double buffer
  __shared__ __align__(16) float wrowL[DD];
  __shared__ __align__(16) float partF[512];
  __shared__ float demL[NN];
  __shared__ float pgumL[2][NN];
  __shared__ unsigned keysL[2 * NT];

  const int b = blockIdx.x, tid = threadIdx.x;
  const int Bn = gridDim.x;
  const int w = tid >> 6, l = tid & 63;
  int ns = *ns_p; if (ns > NT) ns = NT;
  const int greedy = *greedy_p;
  const float Tval = *T_p;
  const float cap0 = *cap_p;

  // ---- stage ----
  {
    const float4* src = (const float4*)(enc + (size_t)b * NN * DD);
    float4* dst = (float4*)qpoolL;
    for (int e = tid; e < NN * DD / 4; e += 512) dst[e] = src[e];
  }
  if (tid < 128) poolB[0][tid] = pool_in[b * DD + tid];
  for (int e = tid; e < 13 * RS; e += 512) Vsh[51 * RS + e] = 0.f;
  if (tid < NN)  demL[tid] = demand[b * NN + tid];
  if (tid < ns) {  // fold_in(key(1234),0), then partitionable split child t
    unsigned a0 = 0u, a1 = 0u;
    tf2x32(0u, 1234u, a0, a1);
    unsigned x0 = 0u, x1 = (unsigned)tid;
    tf2x32(a0, a1, x0, x1);
    keysL[2 * tid] = x0; keysL[2 * tid + 1] = x1;
  }
  __syncthreads();  // S1

  float dem_l = (l < NN) ? demL[l] : 0.f;

  // gumbel(0) (wave 7)
  if (!greedy && tid >= 448) {
    const int gl = tid - 448;
    if (gl < NN)
      pgumL[0][gl] = gumbel_from(keysL[0], keysL[1], (unsigned)(b * NN + gl));
  }
  // wrow partials
  {
    const int c = tid & 127, qd = tid >> 7;
    const float* fr = fc_w + 128 * DD;
    float s = 0.f;
    for (int j = qd * 32; j < qd * 32 + 32; ++j) s += fr[j] * wq[j * DD + c];
    partF[tid] = s;
  }
  __syncthreads();  // S2
  if (tid < 128)
    wrowL[tid] = partF[tid] + partF[tid + 128] + partF[tid + 256] + partF[tid + 384];

  const int g4 = tid >> 7, cc = tid & 127;
  const int n0 = g4 * 13, cnt13 = (g4 == 3) ? 12 : 13;

  // ---- phase A (fused): K, V, T1, T2 in one E pass ----
  {
    float aK[13], aV[13], aT1[13], aT2[13];
#pragma unroll
    for (int r = 0; r < 13; ++r) { aK[r] = 0.f; aV[r] = 0.f; aT1[r] = 0.f; aT2[r] = 0.f; }
    for (int i = 0; i < DD; i += 4) {
      const float k0 = wk[(i + 0) * DD + cc], k1 = wk[(i + 1) * DD + cc];
      const float k2 = wk[(i + 2) * DD + cc], k3 = wk[(i + 3) * DD + cc];
      const float v0 = wv[(i + 0) * DD + cc], v1 = wv[(i + 1) * DD + cc];
      const float v2 = wv[(i + 2) * DD + cc], v3 = wv[(i + 3) * DD + cc];
      const float f0 = fc_w[(i + 0) * DD + cc], f1 = fc_w[(i + 1) * DD + cc];
      const float f2 = fc_w[(i + 2) * DD + cc], f3 = fc_w[(i + 3) * DD + cc];
      const float p0 = wkp[(i + 0) * DD + cc], p1 = wkp[(i + 1) * DD + cc];
      const float p2 = wkp[(i + 2) * DD + cc], p3 = wkp[(i + 3) * DD + cc];
#pragma unroll
      for (int r = 0; r < 13; ++r) {
        if (r < cnt13) {
          const float4 e4 = *(const float4*)&qpoolL[(n0 + r) * DD + i];
          aK[r]  += e4.x * k0 + e4.y * k1 + e4.z * k2 + e4.w * k3;
          aV[r]  += e4.x * v0 + e4.y * v1 + e4.z * v2 + e4.w * v3;
          aT1[r] += e4.x * f0 + e4.y * f1 + e4.z * f2 + e4.w * f3;
          aT2[r] += e4.x * p0 + e4.y * p1 + e4.z * p2 + e4.w * p3;
        }
      }
    }
#pragma unroll
    for (int r = 0; r < 13; ++r) {
      if (r < cnt13) {
        Ksh[(n0 + r) * RS + cc]   = aK[r];
        Vsh[(n0 + r) * RS + cc]   = aV[r];
        EQsh[(n0 + r) * RS + cc]  = aT1[r];
        KP2sh[(n0 + r) * RS + cc] = aT2[r];
      }
    }
  }
  __syncthreads();  // S3

  // ---- phase B (fused, in place): EQ = T1@wq ; KP2 = T2@wo^T ----
  {
    float aEQ[13], aKP[13];
#pragma unroll
    for (int r = 0; r < 13; ++r) { aEQ[r] = 0.f; aKP[r] = 0.f; }
    for (int i = 0; i < DD; i += 4) {
      const float q0 = wq[(i + 0) * DD + cc], q1 = wq[(i + 1) * DD + cc];
      const float q2 = wq[(i + 2) * DD + cc], q3 = wq[(i + 3) * DD + cc];
      const float4 w4 = *(const float4*)&wo[cc * DD + i];
#pragma unroll
      for (int r = 0; r < 13; ++r) {
        if (r < cnt13) {
          const float4 t1 = *(const float4*)&EQsh[(n0 + r) * RS + i];
          const float4 t2 = *(const float4*)&KP2sh[(n0 + r) * RS + i];
          aEQ[r] += t1.x * q0 + t1.y * q1 + t1.z * q2 + t1.w * q3;
          aKP[r] += dot4(t2, w4);
        }
      }
    }
    __syncthreads();  // S4
#pragma unroll
    for (int r = 0; r < 13; ++r) {
      if (r < cnt13) {
        EQsh[(n0 + r) * RS + cc]  = aEQ[r];
        KP2sh[(n0 + r) * RS + cc] = aKP[r];
      }
    }
  }
  __syncthreads();  // S5

  // ---- preload static per-(wave,lane) register slices ----
  const int rowc = (l < NN) ? l : 0;
  const float4* kbase = (const float4*)&Ksh[rowc * RS + w * 16];
  const float4 Kr0 = kbase[0], Kr1 = kbase[1], Kr2 = kbase[2], Kr3 = kbase[3];
  const float4* pbase = (const float4*)&KP2sh[rowc * RS + w * 16];
  const float4 Pr0 = pbase[0], Pr1 = pbase[1], Pr2 = pbase[2], Pr3 = pbase[3];
  const int dq = l >> 4, nn0 = l & 15;
  const float4 Vr0 = *(const float4*)&Vsh[(nn0 +  0) * RS + w * 16 + dq * 4];
  const float4 Vr1 = *(const float4*)&Vsh[(nn0 + 16) * RS + w * 16 + dq * 4];
  const float4 Vr2 = *(const float4*)&Vsh[(nn0 + 32) * RS + w * 16 + dq * 4];
  const float4 Vr3 = *(const float4*)&Vsh[(nn0 + 48) * RS + w * 16 + dq * 4];
  const float4* wbase = (const float4*)&wrowL[w * 16];
  const float4 Wr0 = wbase[0], Wr1 = wbase[1], Wr2 = wbase[2], Wr3 = wbase[3];

  // ---- phase C: pool chain (1 barrier/t), then parallel @wq in place ----
  {
    const int colC = tid >> 2, qrt = tid & 3;
    float wfr[32];
#pragma unroll
    for (int i = 0; i < 32; ++i) wfr[i] = fc1[(qrt * 32 + i) * DD + colC];
    int cur = 0;
    for (int t = 0; t < ns; ++t) {
      float s = 0.f;
#pragma unroll
      for (int i = 0; i < 32; ++i) s += poolB[cur][qrt * 32 + i] * wfr[i];
      s = quad_sum(s);
      if (qrt == 0) {
        qpoolL[t * DD + colC] = s;      // pool_{t+1}
        poolB[cur ^ 1][colC] = s;
      }
      cur ^= 1;
      __syncthreads();
    }
    const int qch = (ns + 3) >> 2;
    const int r0 = g4 * qch;
    const int rcnt = (ns - r0 < qch) ? (ns - r0) : qch;
    float acc[16];
#pragma unroll
    for (int r = 0; r < 16; ++r) acc[r] = 0.f;
    for (int i = 0; i < DD; i += 4) {
      const float q0 = wq[(i + 0) * DD + cc], q1 = wq[(i + 1) * DD + cc];
      const float q2 = wq[(i + 2) * DD + cc], q3 = wq[(i + 3) * DD + cc];
#pragma unroll
      for (int r = 0; r < 16; ++r) {
        if (r < rcnt) {
          const float4 p4 = *(const float4*)&qpoolL[(r0 + r) * DD + i];
          acc[r] += p4.x * q0 + p4.y * q1 + p4.z * q2 + p4.w * q3;
        }
      }
    }
    __syncthreads();
#pragma unroll
    for (int r = 0; r < 16; ++r)
      if (r < rcnt) qpoolL[(r0 + r) * DD + cc] = acc[r];
  }
  __syncthreads();

  // ---- preloop: replicated register state + qv for t=0 ----
  int m1 = (l == 0) ? 1 : 0;
  float dynr = cap0, depotr = 1.f, lpacc0 = 0.f, lpacc1 = 0.f;
  float4 qv0, qv1, qv2, qv3;
  {
    const float4* eq = (const float4*)&EQsh[0 * RS + w * 16];
    const float4* qp = (const float4*)&qpoolL[0 * DD + w * 16];
    qv0.x = eq[0].x + cap0 * Wr0.x + qp[0].x; qv0.y = eq[0].y + cap0 * Wr0.y + qp[0].y;
    qv0.z = eq[0].z + cap0 * Wr0.z + qp[0].z; qv0.w = eq[0].w + cap0 * Wr0.w + qp[0].w;
    qv1.x = eq[1].x + cap0 * Wr1.x + qp[1].x; qv1.y = eq[1].y + cap0 * Wr1.y + qp[1].y;
    qv1.z = eq[1].z + cap0 * Wr1.z + qp[1].z; qv1.w = eq[1].w + cap0 * Wr1.w + qp[1].w;
    qv2.x = eq[2].x + cap0 * Wr2.x + qp[2].x; qv2.y = eq[2].y + cap0 * Wr2.y + qp[2].y;
    qv2.z = eq[2].z + cap0 * Wr2.z + qp[2].z; qv2.w = eq[2].w + cap0 * Wr2.w + qp[2].w;
    qv3.x = eq[3].x + cap0 * Wr3.x + qp[3].x; qv3.y = eq[3].y + cap0 * Wr3.y + qp[3].y;
    qv3.z = eq[3].z + cap0 * Wr3.z + qp[3].z; qv3.w = eq[3].w + cap0 * Wr3.w + qp[3].w;
  }

  // ---- decode: ONE barrier/step ----
  for (int t = 0; t < ns; ++t) {
    // X: head attention + comp partial (all waves)
    {
      const bool maskedl =
          (l == 0) ? (depotr > 0.f)
          : (l < NN ? ((m1 != 0) || (dem_l > dynr)) : true);
      float u1 = NINFF;
      if (l < NN && !maskedl)
        u1 = 0.25f * ((dot4(Kr0, qv0) + dot4(Kr1, qv1)) +
                      (dot4(Kr2, qv2) + dot4(Kr3, qv3)));
      const float mx = wave_max_b(u1);
      const float e = (u1 > NINFF) ? expf(u1 - mx) : 0.f;
      const float S = wave_sum_b(e);
      uL[w * 64 + l] = e;
      asm volatile("s_waitcnt lgkmcnt(0)" ::: "memory");
      __builtin_amdgcn_sched_barrier(0);
      const float a0 = uL[w * 64 + nn0];
      const float a1 = uL[w * 64 + nn0 + 16];
      const float a2 = uL[w * 64 + nn0 + 32];
      const float a3 = uL[w * 64 + nn0 + 48];
      float ax = a0 * Vr0.x + a1 * Vr1.x + a2 * Vr2.x + a3 * Vr3.x;
      float ay = a0 * Vr0.y + a1 * Vr1.y + a2 * Vr2.y + a3 * Vr3.y;
      float az = a0 * Vr0.z + a1 * Vr1.z + a2 * Vr2.z + a3 * Vr3.z;
      float aw = a0 * Vr0.w + a1 * Vr1.w + a2 * Vr2.w + a3 * Vr3.w;
      ax = row16_sum(ax) / S; ay = row16_sum(ay) / S;
      az = row16_sum(az) / S; aw = row16_sum(aw) / S;
      const float g0  = readlanef(ax, 15), g1  = readlanef(ay, 15);
      const float g2  = readlanef(az, 15), g3  = readlanef(aw, 15);
      const float g4g = readlanef(ax, 31), g5  = readlanef(ay, 31);
      const float g6  = readlanef(az, 31), g7  = readlanef(aw, 31);
      const float g8  = readlanef(ax, 47), g9  = readlanef(ay, 47);
      const float g10 = readlanef(az, 47), g11 = readlanef(aw, 47);
      const float g12 = readlanef(ax, 63), g13 = readlanef(ay, 63);
      const float g14 = readlanef(az, 63), g15 = readlanef(aw, 63);
      const float part =
          ((Pr0.x * g0  + Pr0.y * g1  + Pr0.z * g2  + Pr0.w * g3) +
           (Pr1.x * g4g + Pr1.y * g5  + Pr1.z * g6  + Pr1.w * g7)) +
          ((Pr2.x * g8  + Pr2.y * g9  + Pr2.z * g10 + Pr2.w * g11) +
           (Pr3.x * g12 + Pr3.y * g13 + Pr3.z * g14 + Pr3.w * g15));
      pcb2[t & 1][w * 64 + l] = part;
    }
    __syncthreads();   // the ONLY barrier per step
    // Z: replicated sampling + state in every wave
    {
      if (w == 7 && !greedy && t + 1 < ns && l < NN)
        pgumL[(t + 1) & 1][l] =
            gumbel_from(keysL[2 * (t + 1)], keysL[2 * (t + 1) + 1],
                        (unsigned)(b * NN + l));
      const float* pcb = pcb2[t & 1];
      float lgv = NINFF;
      {
        const float p0 = pcb[0 * 64 + l], p1 = pcb[1 * 64 + l];
        const float p2 = pcb[2 * 64 + l], p3 = pcb[3 * 64 + l];
        const float p4 = pcb[4 * 64 + l], p5 = pcb[5 * 64 + l];
        const float p6 = pcb[6 * 64 + l], p7 = pcb[7 * 64 + l];
        const float comp = (((p0 + p1) + (p2 + p3)) + ((p4 + p5) + (p6 + p7))) *
                           0.08838834764831845f;  // 128^-0.5
        const float lg = (10.f * tanhf(comp)) / Tval;
        const bool maskedn =
            (l == 0) ? (depotr > 0.f) : ((m1 != 0) || (dem_l > dynr));
        if (l < NN) lgv = maskedn ? NINFF : lg;
      }
      const float pg = (!greedy && l < NN) ? pgumL[t & 1][l] : 0.f;
      const float pv = (l < NN) ? (lgv + pg) : NINFF;
      const float vmax = wave_max_b(pv);
      const unsigned long long Meq = __ballot(pv == vmax);
      const int best = __ffsll(Meq) - 1;   // first max = jnp.argmax tie-break
      if (l == best) m1 = 1;
      const unsigned long long M = __ballot(m1 != 0);
      const int cntv = (int)__popcll(M & ~1ull);
      const float dem_b = readlanef(dem_l, best);
      dynr = (best == 0) ? cap0 : (dynr - dem_b);
      depotr = (best == 0) ? 1.f : 0.f;
      if (cntv >= NN - 1) depotr = 0.f;
      if (w == 0) {
        lpacc0 += readlanef(lgv, best);
        const float mm = wave_max_b(lgv);
        const float ee = wave_sum_b((lgv > NINFF) ? expf(lgv - mm) : 0.f);
        lpacc1 += mm + logf(ee);
        if (l == 0) out[b * ns + t] = (float)best;
      }
      // prefetch next q slice (wave-uniform values)
      const int qidx = (t + 1 < ns) ? (t + 1) : 0;
      const float4* eq = (const float4*)&EQsh[best * RS + w * 16];
      const float4* qp = (const float4*)&qpoolL[qidx * DD + w * 16];
      qv0.x = eq[0].x + dynr * Wr0.x + qp[0].x; qv0.y = eq[0].y + dynr * Wr0.y + qp[0].y;
      qv0.z = eq[0].z + dynr * Wr0.z + qp[0].z; qv0.w = eq[0].w + dynr * Wr0.w + qp[0].w;
      qv1.x = eq[1].x + dynr * Wr1.x + qp[1].x; qv1.y = eq[1].y + dynr * Wr1.y + qp[1].y;
      qv1.z = eq[1].z + dynr * Wr1.z + qp[1].z; qv1.w = eq[1].w + dynr * Wr1.w + qp[1].w;
      qv2.x = eq[2].x + dynr * Wr2.x + qp[2].x; qv2.y = eq[2].y + dynr * Wr2.y + qp[2].y;
      qv2.z = eq[2].z + dynr * Wr2.z + qp[2].z; qv2.w = eq[2].w + dynr * Wr2.w + qp[2].w;
      qv3.x = eq[3].x + dynr * Wr3.x + qp[3].x; qv3.y = eq[3].y + dynr * Wr3.y + qp[3].y;
      qv3.z = eq[3].z + dynr * Wr3.z + qp[3].z; qv3.w = eq[3].w + dynr * Wr3.w + qp[3].w;
    }
    // no barrier: uL is wave-private, pc/pgum double-buffered (next write is
    // to the other parity and any reuse of this parity is ≥1 barrier away)
  }
  if (tid == 0) out[Bn * ns + b] = lpacc0 - lpacc1;
}

extern "C" void kernel_launch(void* const* d_in, const int* in_sizes, int n_in,
                              void* d_out, int out_size, void* d_ws, size_t ws_size,
                              hipStream_t stream) {
  const float* enc    = (const float*)d_in[0];
  const float* pool   = (const float*)d_in[1];
  const float* cap    = (const float*)d_in[2];
  const float* dem    = (const float*)d_in[3];
  const float* fc_w   = (const float*)d_in[4];
  const float* fc1_w  = (const float*)d_in[5];
  const float* wq     = (const float*)d_in[6];
  const float* wk     = (const float*)d_in[7];
  const float* wv     = (const float*)d_in[8];
  const float* wo     = (const float*)d_in[9];
  const float* wkp    = (const float*)d_in[10];
  const float* Tp     = (const float*)d_in[11];
  const int*   nsp    = (const int*)d_in[12];
  const int*   greedy = (const int*)d_in[14];
  float* out = (float*)d_out;

  const int B = in_sizes[1] / DD;  // pool is (B,128)

  hipLaunchKernelGGL(decode_kernel, dim3(B), dim3(512), 0, stream,
                     enc, pool, cap, dem, fc_w, fc1_w, wq, wk, wv, wo, wkp,
                     Tp, nsp, greedy, out);
}

// Round 11
// 197.876 us; speedup vs baseline: 1.2857x; 1.0414x over previous
//
#include <hip/hip_runtime.h>

#define NN 51
#define DD 128
#define RS 132    // LDS row stride (words)
#define NT 64
#define NINFF (-__builtin_inff())

__device__ __forceinline__ float dot4(const float4 a, const float4 b) {
  return a.x * b.x + a.y * b.y + a.z * b.z + a.w * b.w;
}

// ---- DPP cross-lane (VALU pipe) ----
template<int CTRL>
__device__ __forceinline__ float dppf(float x, float idf) {
  return __int_as_float(__builtin_amdgcn_update_dpp(
      __float_as_int(idf), __float_as_int(x), CTRL, 0xf, 0xf, false));
}
__device__ __forceinline__ float readlanef(float x, int lane) {
  return __int_as_float(__builtin_amdgcn_readlane(__float_as_int(x), lane));
}
__device__ __forceinline__ float bcast63(float x) { return readlanef(x, 63); }
__device__ __forceinline__ float wave_max_b(float x) {
  x = fmaxf(x, dppf<0x111>(x, NINFF));
  x = fmaxf(x, dppf<0x112>(x, NINFF));
  x = fmaxf(x, dppf<0x114>(x, NINFF));
  x = fmaxf(x, dppf<0x118>(x, NINFF));
  x = fmaxf(x, dppf<0x142>(x, NINFF));
  x = fmaxf(x, dppf<0x143>(x, NINFF));
  return bcast63(x);
}
__device__ __forceinline__ float wave_sum_b(float x) {
  x += dppf<0x111>(x, 0.f);
  x += dppf<0x112>(x, 0.f);
  x += dppf<0x114>(x, 0.f);
  x += dppf<0x118>(x, 0.f);
  x += dppf<0x142>(x, 0.f);
  x += dppf<0x143>(x, 0.f);
  return bcast63(x);
}
__device__ __forceinline__ float row16_sum(float x) {  // totals at lanes 15/31/47/63
  x += dppf<0x111>(x, 0.f);
  x += dppf<0x112>(x, 0.f);
  x += dppf<0x114>(x, 0.f);
  x += dppf<0x118>(x, 0.f);
  return x;
}
__device__ __forceinline__ float quad_sum(float x) {   // total in all 4 lanes of quad
  x += dppf<0xB1>(x, 0.f);   // quad_perm [1,0,3,2]
  x += dppf<0x4E>(x, 0.f);   // quad_perm [2,3,0,1]
  return x;
}

// JAX threefry2x32 (20 rounds), exact.
__device__ __forceinline__ void tf2x32(unsigned k0, unsigned k1, unsigned &x0, unsigned &x1) {
  const unsigned ks2 = k0 ^ k1 ^ 0x1BD11BDAu;
  const unsigned ka[5] = {k1, ks2, k0, k1, ks2};
  const unsigned kb[5] = {ks2 + 1u, k0 + 2u, k1 + 3u, ks2 + 4u, k0 + 5u};
  x0 += k0; x1 += k1;
#pragma unroll
  for (int g = 0; g < 5; ++g) {
    const int r0 = (g & 1) ? 17 : 13;
    const int r1 = (g & 1) ? 29 : 15;
    const int r2 = (g & 1) ? 16 : 26;
    const int r3 = (g & 1) ? 24 : 6;
    x0 += x1; x1 = (x1 << r0) | (x1 >> (32 - r0)); x1 ^= x0;
    x0 += x1; x1 = (x1 << r1) | (x1 >> (32 - r1)); x1 ^= x0;
    x0 += x1; x1 = (x1 << r2) | (x1 >> (32 - r2)); x1 ^= x0;
    x0 += x1; x1 = (x1 << r3) | (x1 >> (32 - r3)); x1 ^= x0;
    x0 += ka[g]; x1 += kb[g];
  }
}

__device__ __forceinline__ float gumbel_from(unsigned k0, unsigned k1, unsigned ctr) {
  unsigned x0 = 0u, x1 = ctr;
  tf2x32(k0, k1, x0, x1);
  const unsigned bits = x0 ^ x1;
  const float fl = __uint_as_float((bits >> 9) | 0x3f800000u) - 1.0f;
  const float TINY = 1.17549435e-38f;
  const float uu = fmaxf(TINY, fl + TINY);
  return -logf(-logf(uu));
}

__global__ __launch_bounds__(512, 1) void decode_kernel(
    const float* __restrict__ enc, const float* __restrict__ pool_in,
    const float* __restrict__ cap_p, const float* __restrict__ demand,
    const float* __restrict__ fc_w, const float* __restrict__ fc1,
    const float* __restrict__ wq, const float* __restrict__ wk,
    const float* __restrict__ wv, const float* __restrict__ wo,
    const float* __restrict__ wkp, const float* __restrict__ T_p,
    const int* __restrict__ ns_p, const int* __restrict__ greedy_p,
    float* __restrict__ out) {
  __shared__ __align__(16) float Ksh[NN * RS];
  __shared__ __align__(16) float Vsh[52 * RS];     // row 51 zero
  __shared__ __align__(16) float KP2sh[NN * RS];
  __shared__ __align__(16) float EQsh[NN * RS];
  __shared__ __align__(16) float qpoolL[NT * DD];  // staged enc -> pools -> qpool[t]
  __shared__ __align__(16) float pcb2[2][8 * 64];  // comp partials (aliases partF early)
  __shared__ __align__(16) float poolB[2][DD];     // pool chain double buffer
  __shared__ __align__(16) float wrowL[DD];
  __shared__ __align__(16) float gumT[NT * NN];    // precomputed gumbel table
  __shared__ float demL[NN];
  __shared__ float actsL[NT];
  __shared__ unsigned keysL[2 * NT];

  const int b = blockIdx.x, tid = threadIdx.x;
  const int Bn = gridDim.x;
  const int w = tid >> 6, l = tid & 63;
  int ns = *ns_p; if (ns > NT) ns = NT;
  const int greedy = *greedy_p;
  const float Tval = *T_p;
  const float cap0 = *cap_p;
  float* partF = &pcb2[0][0];   // 512-float alias, preamble only

  // ---- stage ----
  {
    const float4* src = (const float4*)(enc + (size_t)b * NN * DD);
    float4* dst = (float4*)qpoolL;
    for (int e = tid; e < NN * DD / 4; e += 512) dst[e] = src[e];
  }
  if (tid < 128) poolB[0][tid] = pool_in[b * DD + tid];
  if (tid < RS)  Vsh[51 * RS + tid] = 0.f;
  if (tid < NN)  demL[tid] = demand[b * NN + tid];
  if (tid < ns) {  // fold_in(key(1234),0), then partitionable split child t
    unsigned a0 = 0u, a1 = 0u;
    tf2x32(0u, 1234u, a0, a1);
    unsigned x0 = 0u, x1 = (unsigned)tid;
    tf2x32(a0, a1, x0, x1);
    keysL[2 * tid] = x0; keysL[2 * tid + 1] = x1;
  }
  __syncthreads();  // S1

  float dem_l = (l < NN) ? demL[l] : 0.f;

  // gumbel table for all steps (replaces per-step wave-7 gumbel)
  if (!greedy) {
    for (int job = tid; job < ns * NN; job += 512) {
      const int t = job / NN, n = job - t * NN;
      gumT[job] = gumbel_from(keysL[2 * t], keysL[2 * t + 1], (unsigned)(b * NN + n));
    }
  }
  // wrow partials
  {
    const int c = tid & 127, qd = tid >> 7;
    const float* fr = fc_w + 128 * DD;
    float s = 0.f;
    for (int j = qd * 32; j < qd * 32 + 32; ++j) s += fr[j] * wq[j * DD + c];
    partF[tid] = s;
  }
  __syncthreads();  // S2
  if (tid < 128)
    wrowL[tid] = partF[tid] + partF[tid + 128] + partF[tid + 256] + partF[tid + 384];

  const int g4 = tid >> 7, cc = tid & 127;
  const int n0 = g4 * 13, cnt13 = (g4 == 3) ? 12 : 13;

  // ---- phase A (fused): K, V, T1, T2 in one E pass ----
  {
    float aK[13], aV[13], aT1[13], aT2[13];
#pragma unroll
    for (int r = 0; r < 13; ++r) { aK[r] = 0.f; aV[r] = 0.f; aT1[r] = 0.f; aT2[r] = 0.f; }
    for (int i = 0; i < DD; i += 4) {
      const float k0 = wk[(i + 0) * DD + cc], k1 = wk[(i + 1) * DD + cc];
      const float k2 = wk[(i + 2) * DD + cc], k3 = wk[(i + 3) * DD + cc];
      const float v0 = wv[(i + 0) * DD + cc], v1 = wv[(i + 1) * DD + cc];
      const float v2 = wv[(i + 2) * DD + cc], v3 = wv[(i + 3) * DD + cc];
      const float f0 = fc_w[(i + 0) * DD + cc], f1 = fc_w[(i + 1) * DD + cc];
      const float f2 = fc_w[(i + 2) * DD + cc], f3 = fc_w[(i + 3) * DD + cc];
      const float p0 = wkp[(i + 0) * DD + cc], p1 = wkp[(i + 1) * DD + cc];
      const float p2 = wkp[(i + 2) * DD + cc], p3 = wkp[(i + 3) * DD + cc];
#pragma unroll
      for (int r = 0; r < 13; ++r) {
        if (r < cnt13) {
          const float4 e4 = *(const float4*)&qpoolL[(n0 + r) * DD + i];
          aK[r]  += e4.x * k0 + e4.y * k1 + e4.z * k2 + e4.w * k3;
          aV[r]  += e4.x * v0 + e4.y * v1 + e4.z * v2 + e4.w * v3;
          aT1[r] += e4.x * f0 + e4.y * f1 + e4.z * f2 + e4.w * f3;
          aT2[r] += e4.x * p0 + e4.y * p1 + e4.z * p2 + e4.w * p3;
        }
      }
    }
#pragma unroll
    for (int r = 0; r < 13; ++r) {
      if (r < cnt13) {
        Ksh[(n0 + r) * RS + cc]   = aK[r];
        Vsh[(n0 + r) * RS + cc]   = aV[r];
        EQsh[(n0 + r) * RS + cc]  = aT1[r];
        KP2sh[(n0 + r) * RS + cc] = aT2[r];
      }
    }
  }
  __syncthreads();  // S3

  // ---- phase B (fused, in place): EQ = T1@wq ; KP2 = T2@wo^T ----
  {
    float aEQ[13], aKP[13];
#pragma unroll
    for (int r = 0; r < 13; ++r) { aEQ[r] = 0.f; aKP[r] = 0.f; }
    for (int i = 0; i < DD; i += 4) {
      const float q0 = wq[(i + 0) * DD + cc], q1 = wq[(i + 1) * DD + cc];
      const float q2 = wq[(i + 2) * DD + cc], q3 = wq[(i + 3) * DD + cc];
      const float4 w4 = *(const float4*)&wo[cc * DD + i];
#pragma unroll
      for (int r = 0; r < 13; ++r) {
        if (r < cnt13) {
          const float4 t1 = *(const float4*)&EQsh[(n0 + r) * RS + i];
          const float4 t2 = *(const float4*)&KP2sh[(n0 + r) * RS + i];
          aEQ[r] += t1.x * q0 + t1.y * q1 + t1.z * q2 + t1.w * q3;
          aKP[r] += dot4(t2, w4);
        }
      }
    }
    __syncthreads();  // S4
#pragma unroll
    for (int r = 0; r < 13; ++r) {
      if (r < cnt13) {
        EQsh[(n0 + r) * RS + cc]  = aEQ[r];
        KP2sh[(n0 + r) * RS + cc] = aKP[r];
      }
    }
  }
  __syncthreads();  // S5

  // ---- preload static per-(wave,lane) register slices ----
  const int rowc = (l < NN) ? l : 0;
  const float4* kbase = (const float4*)&Ksh[rowc * RS + w * 16];
  const float4 Kr0 = kbase[0], Kr1 = kbase[1], Kr2 = kbase[2], Kr3 = kbase[3];
  const float4* pbase = (const float4*)&KP2sh[rowc * RS + w * 16];
  const float4 Pr0 = pbase[0], Pr1 = pbase[1], Pr2 = pbase[2], Pr3 = pbase[3];
  const int nn0 = l & 15, dq = l >> 4;
  const int vr3 = (nn0 + 48 <= 51) ? (nn0 + 48) : 51;   // rows 52..63 -> zero row (a=0 there)
  const float4 Vr0 = *(const float4*)&Vsh[(nn0 +  0) * RS + w * 16 + dq * 4];
  const float4 Vr1 = *(const float4*)&Vsh[(nn0 + 16) * RS + w * 16 + dq * 4];
  const float4 Vr2 = *(const float4*)&Vsh[(nn0 + 32) * RS + w * 16 + dq * 4];
  const float4 Vr3 = *(const float4*)&Vsh[vr3 * RS + w * 16 + dq * 4];
  const float4* wbase = (const float4*)&wrowL[w * 16];
  const float4 Wr0 = wbase[0], Wr1 = wbase[1], Wr2 = wbase[2], Wr3 = wbase[3];

  // ---- phase C: pool chain (1 barrier/t), then parallel @wq in place ----
  {
    const int colC = tid >> 2, qrt = tid & 3;
    float wfr[32];
#pragma unroll
    for (int i = 0; i < 32; ++i) wfr[i] = fc1[(qrt * 32 + i) * DD + colC];
    int cur = 0;
    for (int t = 0; t < ns; ++t) {
      float s = 0.f;
#pragma unroll
      for (int i = 0; i < 32; ++i) s += poolB[cur][qrt * 32 + i] * wfr[i];
      s = quad_sum(s);
      if (qrt == 0) {
        qpoolL[t * DD + colC] = s;      // pool_{t+1}
        poolB[cur ^ 1][colC] = s;
      }
      cur ^= 1;
      __syncthreads();
    }
    const int qch = (ns + 3) >> 2;
    const int r0 = g4 * qch;
    const int rcnt = (ns - r0 < qch) ? (ns - r0) : qch;
    float acc[16];
#pragma unroll
    for (int r = 0; r < 16; ++r) acc[r] = 0.f;
    for (int i = 0; i < DD; i += 4) {
      const float q0 = wq[(i + 0) * DD + cc], q1 = wq[(i + 1) * DD + cc];
      const float q2 = wq[(i + 2) * DD + cc], q3 = wq[(i + 3) * DD + cc];
#pragma unroll
      for (int r = 0; r < 16; ++r) {
        if (r < rcnt) {
          const float4 p4 = *(const float4*)&qpoolL[(r0 + r) * DD + i];
          acc[r] += p4.x * q0 + p4.y * q1 + p4.z * q2 + p4.w * q3;
        }
      }
    }
    __syncthreads();
#pragma unroll
    for (int r = 0; r < 16; ++r)
      if (r < rcnt) qpoolL[(r0 + r) * DD + cc] = acc[r];
  }
  __syncthreads();

  // ---- preloop: replicated register state + qv for t=0 ----
  int m1 = (l == 0) ? 1 : 0;
  float dynr = cap0, depotr = 1.f, lpacc0 = 0.f, lpacc1 = 0.f;
  float4 qv0, qv1, qv2, qv3;
  {
    const float4* eq = (const float4*)&EQsh[0 * RS + w * 16];
    const float4* qp = (const float4*)&qpoolL[0 * DD + w * 16];
    qv0.x = eq[0].x + cap0 * Wr0.x + qp[0].x; qv0.y = eq[0].y + cap0 * Wr0.y + qp[0].y;
    qv0.z = eq[0].z + cap0 * Wr0.z + qp[0].z; qv0.w = eq[0].w + cap0 * Wr0.w + qp[0].w;
    qv1.x = eq[1].x + cap0 * Wr1.x + qp[1].x; qv1.y = eq[1].y + cap0 * Wr1.y + qp[1].y;
    qv1.z = eq[1].z + cap0 * Wr1.z + qp[1].z; qv1.w = eq[1].w + cap0 * Wr1.w + qp[1].w;
    qv2.x = eq[2].x + cap0 * Wr2.x + qp[2].x; qv2.y = eq[2].y + cap0 * Wr2.y + qp[2].y;
    qv2.z = eq[2].z + cap0 * Wr2.z + qp[2].z; qv2.w = eq[2].w + cap0 * Wr2.w + qp[2].w;
    qv3.x = eq[3].x + cap0 * Wr3.x + qp[3].x; qv3.y = eq[3].y + cap0 * Wr3.y + qp[3].y;
    qv3.z = eq[3].z + cap0 * Wr3.z + qp[3].z; qv3.w = eq[3].w + cap0 * Wr3.w + qp[3].w;
  }

  // ---- decode: ONE barrier/step ----
  for (int t = 0; t < ns; ++t) {
    // X: head attention + comp partial (all waves), PV via bpermute (no LDS buffer)
    {
      const bool maskedl =
          (l == 0) ? (depotr > 0.f)
          : (l < NN ? ((m1 != 0) || (dem_l > dynr)) : true);
      float u1 = NINFF;
      if (l < NN && !maskedl)
        u1 = 0.25f * ((dot4(Kr0, qv0) + dot4(Kr1, qv1)) +
                      (dot4(Kr2, qv2) + dot4(Kr3, qv3)));
      const float mx = wave_max_b(u1);
      const float e = (u1 > NINFF) ? expf(u1 - mx) : 0.f;
      const float a0 = __shfl(e, nn0);
      const float a1 = __shfl(e, nn0 + 16);
      const float a2 = __shfl(e, nn0 + 32);
      const float a3 = __shfl(e, nn0 + 48);
      const float S = wave_sum_b(e);
      float ax = a0 * Vr0.x + a1 * Vr1.x + a2 * Vr2.x + a3 * Vr3.x;
      float ay = a0 * Vr0.y + a1 * Vr1.y + a2 * Vr2.y + a3 * Vr3.y;
      float az = a0 * Vr0.z + a1 * Vr1.z + a2 * Vr2.z + a3 * Vr3.z;
      float aw = a0 * Vr0.w + a1 * Vr1.w + a2 * Vr2.w + a3 * Vr3.w;
      ax = row16_sum(ax) / S; ay = row16_sum(ay) / S;
      az = row16_sum(az) / S; aw = row16_sum(aw) / S;
      const float g0  = readlanef(ax, 15), g1  = readlanef(ay, 15);
      const float g2  = readlanef(az, 15), g3  = readlanef(aw, 15);
      const float g4g = readlanef(ax, 31), g5  = readlanef(ay, 31);
      const float g6  = readlanef(az, 31), g7  = readlanef(aw, 31);
      const float g8  = readlanef(ax, 47), g9  = readlanef(ay, 47);
      const float g10 = readlanef(az, 47), g11 = readlanef(aw, 47);
      const float g12 = readlanef(ax, 63), g13 = readlanef(ay, 63);
      const float g14 = readlanef(az, 63), g15 = readlanef(aw, 63);
      const float part =
          ((Pr0.x * g0  + Pr0.y * g1  + Pr0.z * g2  + Pr0.w * g3) +
           (Pr1.x * g4g + Pr1.y * g5  + Pr1.z * g6  + Pr1.w * g7)) +
          ((Pr2.x * g8  + Pr2.y * g9  + Pr2.z * g10 + Pr2.w * g11) +
           (Pr3.x * g12 + Pr3.y * g13 + Pr3.z * g14 + Pr3.w * g15));
      pcb2[t & 1][w * 64 + l] = part;
    }
    __syncthreads();   // the ONLY barrier per step
    // Z: replicated sampling + state in every wave
    {
      // early best-independent prefetches
      const int qidx = (t + 1 < ns) ? (t + 1) : 0;
      const float4* qp = (const float4*)&qpoolL[qidx * DD + w * 16];
      const float4 qp0 = qp[0], qp1 = qp[1], qp2 = qp[2], qp3 = qp[3];
      const float pg = (!greedy && l < NN) ? gumT[t * NN + l] : 0.f;
      const float* pcb = pcb2[t & 1];
      float lgv = NINFF;
      {
        const float p0 = pcb[0 * 64 + l], p1 = pcb[1 * 64 + l];
        const float p2 = pcb[2 * 64 + l], p3 = pcb[3 * 64 + l];
        const float p4 = pcb[4 * 64 + l], p5 = pcb[5 * 64 + l];
        const float p6 = pcb[6 * 64 + l], p7 = pcb[7 * 64 + l];
        const float comp = (((p0 + p1) + (p2 + p3)) + ((p4 + p5) + (p6 + p7))) *
                           0.08838834764831845f;  // 128^-0.5
        const float lg = (10.f * tanhf(comp)) / Tval;
        const bool maskedn =
            (l == 0) ? (depotr > 0.f) : ((m1 != 0) || (dem_l > dynr));
        if (l < NN) lgv = maskedn ? NINFF : lg;
      }
      const float pv = (l < NN) ? (lgv + pg) : NINFF;
      const float vmax = wave_max_b(pv);
      const unsigned long long Meq = __ballot(pv == vmax);
      const int best = __ffsll(Meq) - 1;   // first max = jnp.argmax tie-break
      if (l == best) m1 = 1;
      const unsigned long long M = __ballot(m1 != 0);
      const int cntv = (int)__popcll(M & ~1ull);
      const float dem_b = readlanef(dem_l, best);
      dynr = (best == 0) ? cap0 : (dynr - dem_b);
      depotr = (best == 0) ? 1.f : 0.f;
      if (cntv >= NN - 1) depotr = 0.f;
      if (w == 1) {          // logp bookkeeping off the wave-0 critical path
        lpacc0 += readlanef(lgv, best);
        const float mm = wave_max_b(lgv);
        const float ee = wave_sum_b((lgv > NINFF) ? expf(lgv - mm) : 0.f);
        lpacc1 += mm + logf(ee);
      }
      if (w == 0 && l == 0) actsL[t] = (float)best;
      // next q slice (wave-uniform values)
      const float4* eq = (const float4*)&EQsh[best * RS + w * 16];
      qv0.x = eq[0].x + dynr * Wr0.x + qp0.x; qv0.y = eq[0].y + dynr * Wr0.y + qp0.y;
      qv0.z = eq[0].z + dynr * Wr0.z + qp0.z; qv0.w = eq[0].w + dynr * Wr0.w + qp0.w;
      qv1.x = eq[1].x + dynr * Wr1.x + qp1.x; qv1.y = eq[1].y + dynr * Wr1.y + qp1.y;
      qv1.z = eq[1].z + dynr * Wr1.z + qp1.z; qv1.w = eq[1].w + dynr * Wr1.w + qp1.w;
      qv2.x = eq[2].x + dynr * Wr2.x + qp2.x; qv2.y = eq[2].y + dynr * Wr2.y + qp2.y;
      qv2.z = eq[2].z + dynr * Wr2.z + qp2.z; qv2.w = eq[2].w + dynr * Wr2.w + qp2.w;
      qv3.x = eq[3].x + dynr * Wr3.x + qp3.x; qv3.y = eq[3].y + dynr * Wr3.y + qp3.y;
      qv3.z = eq[3].z + dynr * Wr3.z + qp3.z; qv3.w = eq[3].w + dynr * Wr3.w + qp3.w;
    }
    // no barrier: pcb double-buffered; gumT/actsL read/written by owning waves only
  }
  __syncthreads();
  if (w == 0 && l < ns) out[b * ns + l] = actsL[l];
  if (w == 1 && l == 0) out[Bn * ns + b] = lpacc0 - lpacc1;
}

extern "C" void kernel_launch(void* const* d_in, const int* in_sizes, int n_in,
                              void* d_out, int out_size, void* d_ws, size_t ws_size,
                              hipStream_t stream) {
  const float* enc    = (const float*)d_in[0];
  const float* pool   = (const float*)d_in[1];
  const float* cap    = (const float*)d_in[2];
  const float* dem    = (const float*)d_in[3];
  const float* fc_w   = (const float*)d_in[4];
  const float* fc1_w  = (const float*)d_in[5];
  const float* wq     = (const float*)d_in[6];
  const float* wk     = (const float*)d_in[7];
  const float* wv     = (const float*)d_in[8];
  const float* wo     = (const float*)d_in[9];
  const float* wkp    = (const float*)d_in[10];
  const float* Tp     = (const float*)d_in[11];
  const int*   nsp    = (const int*)d_in[12];
  const int*   greedy = (const int*)d_in[14];
  float* out = (float*)d_out;

  const int B = in_sizes[1] / DD;  // pool is (B,128)

  hipLaunchKernelGGL(decode_kernel, dim3(B), dim3(512), 0, stream,
                     enc, pool, cap, dem, fc_w, fc1_w, wq, wk, wv, wo, wkp,
                     Tp, nsp, greedy, out);
}